// Round 12
// baseline (851.335 us; speedup 1.0000x reference)
//
#include <hip/hip_runtime.h>
#include <math.h>

#define N_NODES 65536
#define NE      524288
#define DD      128
#define BGRAPH  128
#define NPG     512
#define RATIO_K 128
#define NHEAD   4
#define DHEAD   32
#define APSFULL ((size_t)N_NODES * DD)

typedef short bf16x8 __attribute__((ext_vector_type(8)));
typedef float f32x4 __attribute__((ext_vector_type(4)));

union U8 { unsigned short u[8]; bf16x8 v; };

__device__ __forceinline__ unsigned short f2b(float f) {
  unsigned u = __float_as_uint(f);
  unsigned r = u + 0x7fffu + ((u >> 16) & 1u);   // RTNE
  return (unsigned short)(r >> 16);
}
__device__ __forceinline__ float b2f(unsigned short h) {
  return __uint_as_float(((unsigned)h) << 16);
}
__device__ __forceinline__ void split3(float v, unsigned short& h, unsigned short& m, unsigned short& l) {
  h = f2b(v);
  float vm = v - b2f(h);
  m = f2b(vm);
  l = f2b(vm - b2f(m));
}

// ======================= graph preprocessing =======================

__global__ void count_kernel(const int* __restrict__ dst, int* __restrict__ cnt) {
  int e = blockIdx.x * 256 + threadIdx.x;
  if (e < NE) atomicAdd(&cnt[dst[e]], 1);
}

__global__ void dinv_kernel(const int* __restrict__ cnt, float* __restrict__ dinv) {
  int i = blockIdx.x * 256 + threadIdx.x;
  if (i < N_NODES) dinv[i] = rsqrtf((float)cnt[i] + 1.0f);
}

// per-graph exclusive scan (graph g owns 512 nodes, exactly 4096 edges)
__global__ __launch_bounds__(512) void scan_kernel2(const int* __restrict__ cnt, int* __restrict__ rp) {
  __shared__ int part[512];
  int g = blockIdx.x, t = threadIdx.x;
  int v = cnt[g * 512 + t];
  part[t] = v;
  __syncthreads();
  for (int off = 1; off < 512; off <<= 1) {
    int u = (t >= off) ? part[t - off] : 0;
    __syncthreads();
    part[t] += u;
    __syncthreads();
  }
  rp[g * 512 + t] = g * 4096 + part[t] - v;   // exclusive
  if (g == BGRAPH - 1 && t == 511) rp[N_NODES] = NE;
}

__global__ void scatter_kernel(const int* __restrict__ edge, const int* __restrict__ rp,
                               int* __restrict__ fill, const float* __restrict__ dinv,
                               int* __restrict__ col, float* __restrict__ wgt) {
  int e = blockIdx.x * 256 + threadIdx.x;
  if (e >= NE) return;
  int s = edge[e];
  int d = edge[NE + e];
  int p = rp[d] + atomicAdd(&fill[d], 1);
  col[p] = s;
  wgt[p] = dinv[s] * dinv[d];
}

// ======================= weight prep (all 14 mats in one launch) =======================
struct WPtrs { const float* p[14]; };

__global__ void wprep_all(WPtrs wp, unsigned short* __restrict__ dstBase) {
  int mat = blockIdx.y;
  int idx = blockIdx.x * 256 + threadIdx.x;   // 16384
  const float* __restrict__ W = wp.p[mat];
  unsigned short* __restrict__ dst = dstBase + (size_t)mat * 49152;
  int k = idx >> 7, n = idx & 127;
  float v = W[k * 128 + n];
  unsigned short h, m, l;
  split3(v, h, m, l);
  dst[n * 128 + k] = h;
  dst[16384 + n * 128 + k] = m;
  dst[32768 + n * 128 + k] = l;
}

// ======================= f32 -> 3 bf16 planes =======================
__global__ void split_kernel(const float* __restrict__ src, unsigned short* __restrict__ dst, size_t aps) {
  size_t idx = (size_t)blockIdx.x * 256 + threadIdx.x;
  float4 v = ((const float4*)src)[idx];
  union { unsigned short u[4]; uint2 q; } ph, pm, pl;
  split3(v.x, ph.u[0], pm.u[0], pl.u[0]);
  split3(v.y, ph.u[1], pm.u[1], pl.u[1]);
  split3(v.z, ph.u[2], pm.u[2], pl.u[2]);
  split3(v.w, ph.u[3], pm.u[3], pl.u[3]);
  size_t e = idx * 4;
  *(uint2*)&dst[e] = ph.q;
  *(uint2*)&dst[aps + e] = pm.q;
  *(uint2*)&dst[2 * aps + e] = pl.q;
}

// ======================= MFMA GEMM v7: zero-LDS, zero-barrier, 32-row blocks, high occupancy =======================
// Block: 4 waves, wave w owns cols [w*32, w*32+32); all waves share rows [bx*32, bx*32+32).
// Grid: M/32 -> A read EXACTLY ONCE from HBM; W (96 KB/mat-set) stays L2-resident.
// acc(NW3)=48 + A-frags 24 + B 12 VGPRs -> fits the 128-VGPR cap of (256,4) -> 4 waves/SIMD.
template<int NW, bool RELU, bool RES, bool DUAL>
__global__ __launch_bounds__(256, 4) void mfma_gemm7(
    const unsigned short* __restrict__ A3, size_t aps,
    const unsigned short* __restrict__ Wt,
    const float* __restrict__ bias, const float* __restrict__ bias2,
    const float* __restrict__ res,
    float* __restrict__ out, float* __restrict__ out2) {
  int tid = threadIdx.x;
  int wave = tid >> 6, lane = tid & 63;
  int c16 = lane & 15, kg = lane >> 4;
  size_t row0 = (size_t)blockIdx.x * 32;
  int n0 = wave * 32;

  f32x4 acc[NW][2][2];
  #pragma unroll
  for (int m = 0; m < NW; ++m)
    #pragma unroll
    for (int mi = 0; mi < 2; ++mi)
      #pragma unroll
      for (int ni = 0; ni < 2; ++ni) acc[m][mi][ni] = (f32x4){0.f, 0.f, 0.f, 0.f};

  #pragma unroll
  for (int ks = 0; ks < 4; ++ks) {
    bf16x8 a[2][3];
    #pragma unroll
    for (int mi = 0; mi < 2; ++mi) {
      size_t ro = (row0 + mi * 16 + c16) * 128 + ks * 32 + kg * 8;
      a[mi][0] = *(const bf16x8*)&A3[ro];
      a[mi][1] = *(const bf16x8*)&A3[aps + ro];
      a[mi][2] = *(const bf16x8*)&A3[2 * aps + ro];
    }

    #pragma unroll
    for (int mat = 0; mat < NW; ++mat) {
      #pragma unroll
      for (int ni = 0; ni < 2; ++ni) {
        const unsigned short* wb = Wt + (size_t)mat * 49152 +
            (size_t)(n0 + ni * 16 + c16) * 128 + ks * 32 + kg * 8;
        bf16x8 bh = *(const bf16x8*)&wb[0];
        bf16x8 bm = *(const bf16x8*)&wb[16384];
        bf16x8 bl = *(const bf16x8*)&wb[32768];
        #pragma unroll
        for (int mi = 0; mi < 2; ++mi) {
          acc[mat][mi][ni] = __builtin_amdgcn_mfma_f32_16x16x32_bf16(a[mi][0], bh, acc[mat][mi][ni], 0, 0, 0);
          acc[mat][mi][ni] = __builtin_amdgcn_mfma_f32_16x16x32_bf16(a[mi][0], bm, acc[mat][mi][ni], 0, 0, 0);
          acc[mat][mi][ni] = __builtin_amdgcn_mfma_f32_16x16x32_bf16(a[mi][1], bh, acc[mat][mi][ni], 0, 0, 0);
          acc[mat][mi][ni] = __builtin_amdgcn_mfma_f32_16x16x32_bf16(a[mi][0], bl, acc[mat][mi][ni], 0, 0, 0);
          acc[mat][mi][ni] = __builtin_amdgcn_mfma_f32_16x16x32_bf16(a[mi][2], bh, acc[mat][mi][ni], 0, 0, 0);
          acc[mat][mi][ni] = __builtin_amdgcn_mfma_f32_16x16x32_bf16(a[mi][1], bm, acc[mat][mi][ni], 0, 0, 0);
        }
      }
    }
  }

  // epilogue
  #pragma unroll
  for (int mi = 0; mi < 2; ++mi)
    #pragma unroll
    for (int ni = 0; ni < 2; ++ni) {
      int colg = n0 + ni * 16 + c16;
      #pragma unroll
      for (int r = 0; r < 4; ++r) {
        size_t o = (row0 + mi * 16 + kg * 4 + r) * 128 + colg;
        if (DUAL) {
          out[o]  = acc[0][mi][ni][r] + bias[colg];
          out2[o] = acc[NW - 1][mi][ni][r] + bias2[colg];
        } else if (NW == 3) {
          float g = fmaxf(acc[0][mi][ni][r] + bias[colg], 0.f)
                  + fmaxf(acc[1][mi][ni][r] + bias[128 + colg], 0.f)
                  + fmaxf(acc[2][mi][ni][r] + bias[256 + colg], 0.f);
          out[o] = g;
        } else {
          float g = acc[0][mi][ni][r] + bias[colg];
          if (RELU) g = fmaxf(g, 0.f);
          if (RES) g += res[o];
          out[o] = g;
        }
      }
    }
}

// ======================= f32 GEMM (tiny classifier matmul) =======================
__global__ __launch_bounds__(256) void gemm_k128(
    const float* __restrict__ A, const float* __restrict__ W,
    const float* __restrict__ bias, const float* __restrict__ res,
    float* __restrict__ out, int M, int do_relu) {
  __shared__ float As[8][64];
  __shared__ float Ws[8][128];
  int tid = threadIdx.x;
  int tx = tid & 15;
  int ty = tid >> 4;
  int row0 = blockIdx.x * 64;
  if (row0 >= M) return;
  const float* Ab = A + (size_t)row0 * DD;

  float acc[4][8];
  #pragma unroll
  for (int i = 0; i < 4; ++i)
    #pragma unroll
    for (int j = 0; j < 8; ++j) acc[i][j] = 0.f;

  for (int k0 = 0; k0 < 128; k0 += 8) {
    {
      int e = tid * 2;
      int r = e >> 3, kk = e & 7;
      float2 av = *(const float2*)&Ab[r * DD + k0 + kk];
      As[kk][r] = av.x;
      As[kk + 1][r] = av.y;
    }
    {
      int kk = tid >> 5, c = (tid & 31) * 4;
      float4 wv = *(const float4*)&W[(k0 + kk) * DD + c];
      *(float4*)&Ws[kk][c] = wv;
    }
    __syncthreads();
    #pragma unroll
    for (int kk = 0; kk < 8; ++kk) {
      float4 a4 = *(const float4*)&As[kk][ty * 4];
      float4 b0 = *(const float4*)&Ws[kk][tx * 8];
      float4 b1 = *(const float4*)&Ws[kk][tx * 8 + 4];
      float av[4] = {a4.x, a4.y, a4.z, a4.w};
      float bv[8] = {b0.x, b0.y, b0.z, b0.w, b1.x, b1.y, b1.z, b1.w};
      #pragma unroll
      for (int i = 0; i < 4; ++i)
        #pragma unroll
        for (int j = 0; j < 8; ++j) acc[i][j] += av[i] * bv[j];
    }
    __syncthreads();
  }
  #pragma unroll
  for (int i = 0; i < 4; ++i) {
    int r = row0 + ty * 4 + i;
    size_t base = (size_t)r * DD + tx * 8;
    #pragma unroll
    for (int j = 0; j < 8; ++j) {
      float g = acc[i][j];
      if (bias) g += bias[tx * 8 + j];
      if (do_relu) g = fmaxf(g, 0.f);
      if (res) g += res[base + j];
      out[base + j] = g;
    }
  }
}

// ======================= edge aggregation -> split bf16 planes =======================
__global__ __launch_bounds__(256) void agg4s_kernel(
    const float* __restrict__ H, const int* __restrict__ rp, const int* __restrict__ col,
    const float* __restrict__ wgt, const float* __restrict__ dinv,
    unsigned short* __restrict__ out3) {
  int g = blockIdx.x * 256 + threadIdx.x;
  int node = g >> 5;
  int l = g & 31;
  const float4* H4 = (const float4*)H;
  float dv = dinv[node];
  float4 acc = H4[(size_t)node * 32 + l];
  float sn = dv * dv;
  acc.x *= sn; acc.y *= sn; acc.z *= sn; acc.w *= sn;
  int beg = rp[node], end = rp[node + 1];
  for (int j = beg; j < end; ++j) {
    float w = wgt[j];
    int c = col[j];
    float4 hv = H4[(size_t)c * 32 + l];
    acc.x += w * hv.x; acc.y += w * hv.y; acc.z += w * hv.z; acc.w += w * hv.w;
  }
  union { unsigned short u[4]; uint2 q; } ph, pm, pl;
  split3(acc.x, ph.u[0], pm.u[0], pl.u[0]);
  split3(acc.y, ph.u[1], pm.u[1], pl.u[1]);
  split3(acc.z, ph.u[2], pm.u[2], pl.u[2]);
  split3(acc.w, ph.u[3], pm.u[3], pl.u[3]);
  size_t e = (size_t)node * 128 + l * 4;
  *(uint2*)&out3[e] = ph.q;
  *(uint2*)&out3[APSFULL + e] = pm.q;
  *(uint2*)&out3[2 * APSFULL + e] = pl.q;
}

// ======================= per-node double dot product =======================
__global__ __launch_bounds__(256) void dot2_kernel(
    const float* __restrict__ X, const float* __restrict__ w1, const float* __restrict__ w2,
    float* __restrict__ t1, float* __restrict__ t2) {
  int node = (blockIdx.x * 256 + threadIdx.x) >> 6;
  int lane = threadIdx.x & 63;
  if (node >= N_NODES) return;
  const float* xr = X + (size_t)node * DD;
  float a = xr[lane], b = xr[lane + 64];
  float s1 = a * w1[lane] + b * w1[lane + 64];
  float s2 = a * w2[lane] + b * w2[lane + 64];
  #pragma unroll
  for (int off = 32; off > 0; off >>= 1) {
    s1 += __shfl_down(s1, off);
    s2 += __shfl_down(s2, off);
  }
  if (lane == 0) { t1[node] = s1; t2[node] = s2; }
}

// ======================= GLA score =======================
__global__ void score_kernel(const float* __restrict__ t1, const float* __restrict__ t2,
                             const int* __restrict__ rp, const int* __restrict__ col,
                             const float* __restrict__ wgt, const float* __restrict__ dinv,
                             const float* __restrict__ b1p, const float* __restrict__ b2p,
                             float* __restrict__ out) {
  int i = blockIdx.x * 256 + threadIdx.x;
  if (i >= N_NODES) return;
  float dv = dinv[i];
  float a2 = dv * dv * t2[i] + b2p[0];
  int beg = rp[i], end = rp[i + 1];
  for (int j = beg; j < end; ++j) a2 += wgt[j] * t2[col[j]];
  out[i] = 0.5f * (t1[i] + b1p[0]) + 0.5f * a2;
}

// ======================= layer-weight softmax + combine (float4) =======================
__global__ void xf_kernel(const float* __restrict__ x1, const float* __restrict__ x2,
                          const float* __restrict__ x3, const float* __restrict__ sc,
                          float* __restrict__ xf) {
  size_t idx = (size_t)blockIdx.x * 256 + threadIdx.x;   // over N_NODES*32
  int i = (int)(idx >> 5);
  float s0 = sc[i], s1 = sc[N_NODES + i], s2 = sc[2 * N_NODES + i];
  float mx = fmaxf(s0, fmaxf(s1, s2));
  float e0 = __expf(s0 - mx), e1 = __expf(s1 - mx), e2 = __expf(s2 - mx);
  float inv = 1.f / (e0 + e1 + e2);
  e0 *= inv; e1 *= inv; e2 *= inv;
  float4 a = ((const float4*)x1)[idx];
  float4 b = ((const float4*)x2)[idx];
  float4 c = ((const float4*)x3)[idx];
  float4 o;
  o.x = e0 * a.x + e1 * b.x + e2 * c.x;
  o.y = e0 * a.y + e1 * b.y + e2 * c.y;
  o.z = e0 * a.z + e1 * b.z + e2 * c.z;
  o.w = e0 * a.w + e1 * b.w + e2 * c.w;
  ((float4*)xf)[idx] = o;
}

// ======================= top-k (stable descending) =======================
__global__ __launch_bounds__(512) void topk_kernel(const float* __restrict__ score,
                                                   int* __restrict__ idxO, float* __restrict__ valO) {
  int b = blockIdx.x;
  int t = threadIdx.x;
  __shared__ float s[512];
  float v = score[b * NPG + t];
  s[t] = v;
  __syncthreads();
  int rank = 0;
  for (int j = 0; j < 512; ++j) {
    float u = s[j];
    rank += (u > v) || (u == v && j < t);
  }
  if (rank < RATIO_K) { idxO[b * RATIO_K + rank] = t; valO[b * RATIO_K + rank] = v; }
}

// ======================= pooled gather * tanh(val) =======================
__global__ void xp_kernel(const float* __restrict__ xf, const int* __restrict__ idx,
                          const float* __restrict__ vals, float* __restrict__ xp) {
  size_t e = (size_t)blockIdx.x * 256 + threadIdx.x;
  int b = (int)(e >> 14);
  int r = (int)((e >> 7) & 127);
  int f = (int)(e & 127);
  float tv = tanhf(vals[b * RATIO_K + r]);
  int node = idx[b * RATIO_K + r];
  xp[e] = xf[((size_t)b * NPG + node) * DD + f] * tv;
}

// ======================= MFMA flash attention =======================
__global__ __launch_bounds__(256) void attn_mfma_kernel(
    const float* __restrict__ Q, const float* __restrict__ K,
    const float* __restrict__ V, float* __restrict__ O) {
  int bb = blockIdx.x >> 2, h = blockIdx.x & 3;
  int tid = threadIdx.x;
  int wave = tid >> 6, lane = tid & 63;
  int c16 = lane & 15, kg = lane >> 4;
  int qbase = wave * 32;
  const float cscale = 0.088388347648318447f;

  __shared__ float Vs[64][34];
  __shared__ unsigned char PwB[4][32 * 144];

  bf16x8 Qh[2], Ql[2];
  #pragma unroll
  for (int qt = 0; qt < 2; ++qt) {
    const float* qp = Q + ((size_t)bb * 128 + qbase + qt * 16 + c16) * 128 + h * 32 + kg * 8;
    float4 f0 = *(const float4*)qp;
    float4 f1 = *(const float4*)(qp + 4);
    float f[8] = {f0.x, f0.y, f0.z, f0.w, f1.x, f1.y, f1.z, f1.w};
    U8 hh, ll;
    #pragma unroll
    for (int j = 0; j < 8; ++j) { hh.u[j] = f2b(f[j]); ll.u[j] = f2b(f[j] - b2f(hh.u[j])); }
    Qh[qt] = hh.v; Ql[qt] = ll.v;
  }

  float m2[2] = {-3.0e38f, -3.0e38f};
  float l2[2] = {0.f, 0.f};
  f32x4 od[2][2];
  #pragma unroll
  for (int dt = 0; dt < 2; ++dt)
    #pragma unroll
    for (int qt = 0; qt < 2; ++qt) od[dt][qt] = (f32x4){0.f, 0.f, 0.f, 0.f};

  for (int kc = 0; kc < NPG; kc += 64) {
    if (kc) __syncthreads();
    {
      int j = tid >> 2, grp = tid & 3;
      const float* vp = V + ((size_t)bb * NPG + kc + j) * 128 + h * 32 + grp * 8;
      float4 v0 = *(const float4*)vp;
      float4 v1 = *(const float4*)(vp + 4);
      float* d = &Vs[j][grp * 8];
      *(float2*)&d[0] = make_float2(v0.x, v0.y);
      *(float2*)&d[2] = make_float2(v0.z, v0.w);
      *(float2*)&d[4] = make_float2(v1.x, v1.y);
      *(float2*)&d[6] = make_float2(v1.z, v1.w);
    }
    __syncthreads();

    f32x4 sac[2][4];
    #pragma unroll
    for (int qt = 0; qt < 2; ++qt)
      #pragma unroll
      for (int kt = 0; kt < 4; ++kt) sac[qt][kt] = (f32x4){0.f, 0.f, 0.f, 0.f};

    #pragma unroll
    for (int kt = 0; kt < 4; ++kt) {
      const float* kp = K + ((size_t)bb * NPG + kc + kt * 16 + c16) * 128 + h * 32 + kg * 8;
      float4 f0 = *(const float4*)kp;
      float4 f1 = *(const float4*)(kp + 4);
      float f[8] = {f0.x, f0.y, f0.z, f0.w, f1.x, f1.y, f1.z, f1.w};
      U8 hh, ll;
      #pragma unroll
      for (int j = 0; j < 8; ++j) { hh.u[j] = f2b(f[j]); ll.u[j] = f2b(f[j] - b2f(hh.u[j])); }
      #pragma unroll
      for (int qt = 0; qt < 2; ++qt) {
        sac[qt][kt] = __builtin_amdgcn_mfma_f32_16x16x32_bf16(hh.v, Qh[qt], sac[qt][kt], 0, 0, 0);
        sac[qt][kt] = __builtin_amdgcn_mfma_f32_16x16x32_bf16(hh.v, Ql[qt], sac[qt][kt], 0, 0, 0);
        sac[qt][kt] = __builtin_amdgcn_mfma_f32_16x16x32_bf16(ll.v, Qh[qt], sac[qt][kt], 0, 0, 0);
      }
    }

    float pj[2][16];
    float scl2[2];
    #pragma unroll
    for (int qt = 0; qt < 2; ++qt) {
      float mc = -3.0e38f;
      #pragma unroll
      for (int kt = 0; kt < 4; ++kt)
        #pragma unroll
        for (int r = 0; r < 4; ++r) {
          float v = sac[qt][kt][r] * cscale;
          pj[qt][kt * 4 + r] = v;
          mc = fmaxf(mc, v);
        }
      mc = fmaxf(mc, __shfl_xor(mc, 16));
      mc = fmaxf(mc, __shfl_xor(mc, 32));
      float mnew = fmaxf(m2[qt], mc);
      float scl = __expf(m2[qt] - mnew);
      float ls = 0.f;
      #pragma unroll
      for (int i = 0; i < 16; ++i) {
        float e = __expf(pj[qt][i] - mnew);
        pj[qt][i] = e;
        ls += e;
      }
      ls += __shfl_xor(ls, 16);
      ls += __shfl_xor(ls, 32);
      l2[qt] = l2[qt] * scl + ls;
      m2[qt] = mnew;
      scl2[qt] = scl;
    }
    #pragma unroll
    for (int dt = 0; dt < 2; ++dt)
      #pragma unroll
      for (int qt = 0; qt < 2; ++qt) {
        #pragma unroll
        for (int r = 0; r < 4; ++r) od[dt][qt][r] *= scl2[qt];
      }

    #pragma unroll
    for (int qt = 0; qt < 2; ++qt) {
      int q32 = qt * 16 + c16;
      unsigned char* pb = &PwB[wave][q32 * 144];
      unsigned sw = (unsigned)((q32 & 7) << 4);
      #pragma unroll
      for (int kt = 0; kt < 4; ++kt)
        #pragma unroll
        for (int rp = 0; rp < 2; ++rp) {
          unsigned pk = (unsigned)f2b(pj[qt][kt * 4 + 2 * rp]) |
                        ((unsigned)f2b(pj[qt][kt * 4 + 2 * rp + 1]) << 16);
          *(unsigned*)&pb[((unsigned)(kt * 32 + kg * 8 + 4 * rp)) ^ sw] = pk;
        }
    }

    #pragma unroll
    for (int kw = 0; kw < 2; ++kw) {
      bf16x8 Pb[2];
      #pragma unroll
      for (int qt = 0; qt < 2; ++qt) {
        int q32 = qt * 16 + c16;
        Pb[qt] = *(const bf16x8*)&PwB[wave][q32 * 144 +
                   (((unsigned)(kw * 64 + kg * 16)) ^ ((unsigned)((q32 & 7) << 4)))];
      }
      #pragma unroll
      for (int dt = 0; dt < 2; ++dt) {
        U8 vh, vl;
        #pragma unroll
        for (int j = 0; j < 8; ++j) {
          float v = Vs[kw * 32 + kg * 8 + j][dt * 16 + c16];
          vh.u[j] = f2b(v);
          vl.u[j] = f2b(v - b2f(vh.u[j]));
        }
        #pragma unroll
        for (int qt = 0; qt < 2; ++qt) {
          od[dt][qt] = __builtin_amdgcn_mfma_f32_16x16x32_bf16(vh.v, Pb[qt], od[dt][qt], 0, 0, 0);
          od[dt][qt] = __builtin_amdgcn_mfma_f32_16x16x32_bf16(vl.v, Pb[qt], od[dt][qt], 0, 0, 0);
        }
      }
    }
  }

  #pragma unroll
  for (int qt = 0; qt < 2; ++qt) {
    float inv = 1.f / l2[qt];
    size_t row = (size_t)bb * 128 + qbase + qt * 16 + c16;
    #pragma unroll
    for (int dt = 0; dt < 2; ++dt)
      #pragma unroll
      for (int r = 0; r < 4; ++r) {
        int colg = h * 32 + dt * 16 + kg * 4 + r;
        O[row * 128 + colg] = Q[row * 128 + colg] + od[dt][qt][r] * inv;
      }
  }
}

// ======================= conv1d readout =======================
__global__ void readout_kernel(const float* __restrict__ O2, const float* __restrict__ ro_w,
                               const float* __restrict__ ro_b, float* __restrict__ xg) {
  int idx = blockIdx.x * 256 + threadIdx.x;
  int b = idx >> 7, d = idx & 127;
  float s = ro_b[0];
  for (int r = 0; r < RATIO_K; ++r) s += ro_w[r] * O2[((size_t)b * RATIO_K + r) * DD + d];
  xg[idx] = s;
}

// ======================= classifier head =======================
__global__ __launch_bounds__(64) void head_kernel(const float* __restrict__ hc,
                                                  const float* __restrict__ c2w,
                                                  const float* __restrict__ c2b,
                                                  float* __restrict__ out) {
  int b = blockIdx.x, t = threadIdx.x;
  __shared__ float z[10];
  __shared__ float lse_s;
  if (t < 10) {
    float s = c2b[t];
    for (int k = 0; k < 128; ++k) s += hc[b * 128 + k] * c2w[k * 10 + t];
    z[t] = s;
  }
  __syncthreads();
  if (t == 0) {
    float mx = z[0];
    for (int c = 1; c < 10; ++c) mx = fmaxf(mx, z[c]);
    float sum = 0.f;
    for (int c = 0; c < 10; ++c) sum += expf(z[c] - mx);
    lse_s = mx + logf(sum);
  }
  __syncthreads();
  if (t < 10) out[b * 10 + t] = z[t] - lse_s;
}

// ======================= launcher =======================
extern "C" void kernel_launch(void* const* d_in, const int* in_sizes, int n_in,
                              void* d_out, int out_size, void* d_ws, size_t ws_size,
                              hipStream_t stream) {
  const float* x       = (const float*)d_in[0];
  const int*   edge    = (const int*)d_in[1];
  const float* enc_w   = (const float*)d_in[2];
  const float* enc_b   = (const float*)d_in[3];
  const float* gconv_w = (const float*)d_in[4];
  const float* gconv_b = (const float*)d_in[5];
  const float* wg1_w   = (const float*)d_in[6];
  const float* wg1_b   = (const float*)d_in[7];
  const float* wg2_w   = (const float*)d_in[8];
  const float* wg2_b   = (const float*)d_in[9];
  const float* pg1_w   = (const float*)d_in[10];
  const float* pg1_b   = (const float*)d_in[11];
  const float* pg2_w   = (const float*)d_in[12];
  const float* pg2_b   = (const float*)d_in[13];
  const float* q_w     = (const float*)d_in[14];
  const float* q_b     = (const float*)d_in[15];
  const float* k_w     = (const float*)d_in[16];
  const float* k_b     = (const float*)d_in[17];
  const float* v_w     = (const float*)d_in[18];
  const float* v_b     = (const float*)d_in[19];
  const float* o_w     = (const float*)d_in[20];
  const float* o_b     = (const float*)d_in[21];
  const float* ro_w    = (const float*)d_in[22];
  const float* ro_b    = (const float*)d_in[23];
  const float* c1_w    = (const float*)d_in[24];
  const float* c1_b    = (const float*)d_in[25];
  const float* c2_w    = (const float*)d_in[26];
  const float* c2_b    = (const float*)d_in[27];

  float* outp = (float*)d_out;

  const size_t S = (size_t)N_NODES * DD;
  float* ws    = (float*)d_ws;
  float* slot0 = ws;            // h, then xf
  float* slot1 = ws + S;        // x1, then K
  float* slot2 = ws + 2 * S;    // x2, then V
  float* slot3 = ws + 3 * S;    // x3, then xp/Q/O/O2
  float* smallf = ws + 4 * S;
  int*   cnt  = (int*)smallf;
  int*   fill = cnt + N_NODES;
  int*   rp   = fill + N_NODES;
  int*   col  = rp + N_NODES + 8;
  float* wgt  = (float*)(col + NE);
  float* dinv = wgt + NE;
  float* sc   = dinv + N_NODES;
  float* t1   = sc + 3 * N_NODES;
  float* t2   = t1 + N_NODES;
  float* score = t2 + N_NODES;
  int*   tidx = (int*)(score + N_NODES);
  float* tval = (float*)(tidx + BGRAPH * RATIO_K);
  float* hcbuf = tval + BGRAPH * RATIO_K;
  unsigned short* wsW = (unsigned short*)(hcbuf + BGRAPH * DD);  // 14 * 49152 ushorts
  unsigned short* A3  = wsW + 14 * 49152;                        // 3 * S ushorts

  const size_t SP = (size_t)BGRAPH * RATIO_K * DD;
  float* xp = slot3;
  float* Qm = slot3 + SP;
  float* Om = slot3 + 2 * SP;
  float* O2 = slot3 + 3 * SP;

  // ---- graph preprocessing ----
  hipMemsetAsync(cnt, 0, N_NODES * sizeof(int), stream);
  hipMemsetAsync(fill, 0, N_NODES * sizeof(int), stream);
  count_kernel<<<NE / 256, 256, 0, stream>>>(edge + NE, cnt);
  dinv_kernel<<<N_NODES / 256, 256, 0, stream>>>(cnt, dinv);
  scan_kernel2<<<BGRAPH, 512, 0, stream>>>(cnt, rp);
  scatter_kernel<<<NE / 256, 256, 0, stream>>>(edge, rp, fill, dinv, col, wgt);

  // ---- weight prep (one launch, 14 mats) ----
  WPtrs wp;
  wp.p[0] = enc_w;
  for (int i = 0; i < 9; ++i) wp.p[1 + i] = gconv_w + (size_t)i * DD * DD;
  wp.p[10] = k_w; wp.p[11] = v_w; wp.p[12] = q_w; wp.p[13] = o_w;
  wprep_all<<<dim3(64, 14), 256, 0, stream>>>(wp, wsW);

  // ---- encoder ----
  split_kernel<<<(int)(S / 1024), 256, 0, stream>>>(x, A3, S);
  mfma_gemm7<1, false, false, false><<<2048, 256, 0, stream>>>(
      A3, S, wsW, enc_b, nullptr, nullptr, slot0, nullptr);

  // ---- 3 GCN layers ----
  float* lin[4] = {slot0, slot1, slot2, slot3};
  const int AGG_GRID = (N_NODES * 32) / 256;
  for (int l = 0; l < 3; ++l) {
    const float* hin = lin[l];
    float* hout = lin[l + 1];
    agg4s_kernel<<<AGG_GRID, 256, 0, stream>>>(hin, rp, col, wgt, dinv, A3);
    mfma_gemm7<3, true, false, false><<<2048, 256, 0, stream>>>(
        A3, S, wsW + (size_t)(1 + l * 3) * 49152, gconv_b + (size_t)l * 3 * DD,
        nullptr, nullptr, hout, nullptr);
    dot2_kernel<<<N_NODES / 4, 256, 0, stream>>>(hout, wg1_w, wg2_w, t1, t2);
    score_kernel<<<N_NODES / 256, 256, 0, stream>>>(t1, t2, rp, col, wgt, dinv, wg1_b, wg2_b, sc + (size_t)l * N_NODES);
  }

  // ---- xf ----
  float* xf = slot0;
  xf_kernel<<<(N_NODES * 32) / 256, 256, 0, stream>>>(slot1, slot2, slot3, sc, xf);

  // ---- pooling score + top-k ----
  dot2_kernel<<<N_NODES / 4, 256, 0, stream>>>(xf, pg1_w, pg2_w, t1, t2);
  score_kernel<<<N_NODES / 256, 256, 0, stream>>>(t1, t2, rp, col, wgt, dinv, pg1_b, pg2_b, score);
  topk_kernel<<<BGRAPH, 512, 0, stream>>>(score, tidx, tval);
  xp_kernel<<<(BGRAPH * RATIO_K * DD) / 256, 256, 0, stream>>>(xf, tidx, tval, xp);

  // ---- Q from split(xp) ----
  split_kernel<<<(int)(SP / 1024), 256, 0, stream>>>(xp, A3, SP);
  mfma_gemm7<1, false, false, false><<<512, 256, 0, stream>>>(
      A3, SP, wsW + 12 * 49152UL, q_b, nullptr, nullptr, Qm, nullptr);

  // ---- shared aggregation(+split) of xf; fused K+V GEMM ----
  agg4s_kernel<<<AGG_GRID, 256, 0, stream>>>(xf, rp, col, wgt, dinv, A3);
  mfma_gemm7<2, false, false, true><<<2048, 256, 0, stream>>>(
      A3, S, wsW + 10 * 49152UL, k_b, v_b, nullptr, slot1, slot2);

  // ---- attention (MFMA flash) ----
  attn_mfma_kernel<<<BGRAPH * NHEAD, 256, 0, stream>>>(Qm, slot1, slot2, Om);

  // ---- O2 = Om + relu(Om @ o_w + o_b) ----
  split_kernel<<<(int)(SP / 1024), 256, 0, stream>>>(Om, A3, SP);
  mfma_gemm7<1, true, true, false><<<512, 256, 0, stream>>>(
      A3, SP, wsW + 13 * 49152UL, o_b, nullptr, Om, O2, nullptr);

  // ---- readout -> xg ----
  float* xg = outp + BGRAPH * 10;
  readout_kernel<<<(BGRAPH * DD) / 256, 256, 0, stream>>>(O2, ro_w, ro_b, xg);

  // ---- classifier ----
  gemm_k128<<<BGRAPH / 64, 256, 0, stream>>>(xg, c1_w, c1_b, nullptr, hcbuf, BGRAPH, 1);
  head_kernel<<<BGRAPH, 64, 0, stream>>>(hcbuf, c2_w, c2_b, outp);
}

// Round 13
// 677.178 us; speedup vs baseline: 1.2572x; 1.2572x over previous
//
#include <hip/hip_runtime.h>
#include <math.h>

#define N_NODES 65536
#define NE      524288
#define DD      128
#define BGRAPH  128
#define NPG     512
#define RATIO_K 128
#define NHEAD   4
#define DHEAD   32

typedef short bf16x8 __attribute__((ext_vector_type(8)));
typedef float f32x4 __attribute__((ext_vector_type(4)));

union U8 { unsigned short u[8]; bf16x8 v; };

__device__ __forceinline__ unsigned short f2b(float f) {
  unsigned u = __float_as_uint(f);
  unsigned r = u + 0x7fffu + ((u >> 16) & 1u);   // RTNE
  return (unsigned short)(r >> 16);
}
__device__ __forceinline__ float b2f(unsigned short h) {
  return __uint_as_float(((unsigned)h) << 16);
}
__device__ __forceinline__ void split3(float v, unsigned short& h, unsigned short& m, unsigned short& l) {
  h = f2b(v);
  float vm = v - b2f(h);
  m = f2b(vm);
  l = f2b(vm - b2f(m));
}

// ======================= graph preprocessing =======================

__global__ void count_kernel(const int* __restrict__ dst, int* __restrict__ cnt) {
  int e = blockIdx.x * 256 + threadIdx.x;
  if (e < NE) atomicAdd(&cnt[dst[e]], 1);
}

__global__ void dinv_kernel(const int* __restrict__ cnt, float* __restrict__ dinv) {
  int i = blockIdx.x * 256 + threadIdx.x;
  if (i < N_NODES) dinv[i] = rsqrtf((float)cnt[i] + 1.0f);
}

// per-graph exclusive scan (graph g owns 512 nodes, exactly 4096 edges)
__global__ __launch_bounds__(512) void scan_kernel2(const int* __restrict__ cnt, int* __restrict__ rp) {
  __shared__ int part[512];
  int g = blockIdx.x, t = threadIdx.x;
  int v = cnt[g * 512 + t];
  part[t] = v;
  __syncthreads();
  for (int off = 1; off < 512; off <<= 1) {
    int u = (t >= off) ? part[t - off] : 0;
    __syncthreads();
    part[t] += u;
    __syncthreads();
  }
  rp[g * 512 + t] = g * 4096 + part[t] - v;   // exclusive
  if (g == BGRAPH - 1 && t == 511) rp[N_NODES] = NE;
}

__global__ void scatter_kernel(const int* __restrict__ edge, const int* __restrict__ rp,
                               int* __restrict__ fill, const float* __restrict__ dinv,
                               int* __restrict__ col, float* __restrict__ wgt) {
  int e = blockIdx.x * 256 + threadIdx.x;
  if (e >= NE) return;
  int s = edge[e];
  int d = edge[NE + e];
  int p = rp[d] + atomicAdd(&fill[d], 1);
  col[p] = s;
  wgt[p] = dinv[s] * dinv[d];
}

// ======================= weight prep (all 14 mats in one launch) =======================
struct WPtrs { const float* p[14]; };

__global__ void wprep_all(WPtrs wp, unsigned short* __restrict__ dstBase) {
  int mat = blockIdx.y;
  int idx = blockIdx.x * 256 + threadIdx.x;   // 16384
  const float* __restrict__ W = wp.p[mat];
  unsigned short* __restrict__ dst = dstBase + (size_t)mat * 49152;
  int k = idx >> 7, n = idx & 127;
  float v = W[k * 128 + n];
  unsigned short h, m, l;
  split3(v, h, m, l);
  dst[n * 128 + k] = h;
  dst[16384 + n * 128 + k] = m;
  dst[32768 + n * 128 + k] = l;
}

// ======================= MFMA GEMM v8: v4 structure, f32 A with in-register split =======================
// Block: 4 waves 2x2 -> 64 rows x 64 cols. Wave: 32 rows x 32 cols (2 mi x 2 ni).
// Per ks: stage W k-slice [NW*3][64n][32k] (40-short padded rows) in LDS; load A rows as f32
// and split3 in-register (bit-identical to pre-split planes); NW*2*2*6 MFMAs per wave per ks.
// Grid: (2 n-blocks, M/64).
#define WROW 40   // padded row stride in ushorts (80 B)

template<int NW, bool RELU, bool RES, bool DUAL>
__global__ __launch_bounds__(256, 2) void mfma_gemm8(
    const float* __restrict__ A,
    const unsigned short* __restrict__ Wt,
    const float* __restrict__ bias, const float* __restrict__ bias2,
    const float* __restrict__ res,
    float* __restrict__ out, float* __restrict__ out2) {
  __shared__ unsigned short Wlds[NW * 3 * 64 * WROW];
  int tid = threadIdx.x;
  int wave = tid >> 6, lane = tid & 63;
  int c16 = lane & 15, kg = lane >> 4;
  int wrow = (wave >> 1) * 32;
  int wcol = (wave & 1) * 32;
  size_t row0 = (size_t)blockIdx.y * 64 + wrow;
  int n0 = blockIdx.x * 64;

  f32x4 acc[NW][2][2];
  #pragma unroll
  for (int m = 0; m < NW; ++m)
    #pragma unroll
    for (int mi = 0; mi < 2; ++mi)
      #pragma unroll
      for (int ni = 0; ni < 2; ++ni) acc[m][mi][ni] = (f32x4){0.f, 0.f, 0.f, 0.f};

  for (int ks = 0; ks < 4; ++ks) {
    if (ks) __syncthreads();
    // stage W k-slice: NW*3 (mat,plane) x 64 n-rows x 32 k
    #pragma unroll
    for (int i = 0; i < NW * 3; ++i) {
      int c = tid + i * 256;
      int u4 = c & 3;
      int n = (c >> 2) & 63;
      int mp = c >> 8;
      *(uint4*)&Wlds[(mp * 64 + n) * WROW + u4 * 8] =
          *(const uint4*)&Wt[(size_t)mp * 16384 + (n0 + n) * 128 + ks * 32 + u4 * 8];
    }
    __syncthreads();

    // A frags: load f32, split in-register (same values as pre-split planes)
    bf16x8 a[2][3];
    #pragma unroll
    for (int mi = 0; mi < 2; ++mi) {
      const float* ap = A + (row0 + mi * 16 + c16) * 128 + ks * 32 + kg * 8;
      float4 f0 = *(const float4*)ap;
      float4 f1 = *(const float4*)(ap + 4);
      float f[8] = {f0.x, f0.y, f0.z, f0.w, f1.x, f1.y, f1.z, f1.w};
      U8 hh, mm, ll;
      #pragma unroll
      for (int j = 0; j < 8; ++j) split3(f[j], hh.u[j], mm.u[j], ll.u[j]);
      a[mi][0] = hh.v; a[mi][1] = mm.v; a[mi][2] = ll.v;
    }

    #pragma unroll
    for (int mat = 0; mat < NW; ++mat) {
      #pragma unroll
      for (int ni = 0; ni < 2; ++ni) {
        int nrow = (wcol >> 4) + ni;
        int off = ((mat * 3) * 64 + nrow * 16 + c16) * WROW + kg * 8;
        bf16x8 bh = *(const bf16x8*)&Wlds[off];
        bf16x8 bm = *(const bf16x8*)&Wlds[off + 64 * WROW];
        bf16x8 bl = *(const bf16x8*)&Wlds[off + 128 * WROW];
        #pragma unroll
        for (int mi = 0; mi < 2; ++mi) {
          acc[mat][mi][ni] = __builtin_amdgcn_mfma_f32_16x16x32_bf16(a[mi][0], bh, acc[mat][mi][ni], 0, 0, 0);
          acc[mat][mi][ni] = __builtin_amdgcn_mfma_f32_16x16x32_bf16(a[mi][0], bm, acc[mat][mi][ni], 0, 0, 0);
          acc[mat][mi][ni] = __builtin_amdgcn_mfma_f32_16x16x32_bf16(a[mi][1], bh, acc[mat][mi][ni], 0, 0, 0);
          acc[mat][mi][ni] = __builtin_amdgcn_mfma_f32_16x16x32_bf16(a[mi][0], bl, acc[mat][mi][ni], 0, 0, 0);
          acc[mat][mi][ni] = __builtin_amdgcn_mfma_f32_16x16x32_bf16(a[mi][2], bh, acc[mat][mi][ni], 0, 0, 0);
          acc[mat][mi][ni] = __builtin_amdgcn_mfma_f32_16x16x32_bf16(a[mi][1], bm, acc[mat][mi][ni], 0, 0, 0);
        }
      }
    }
  }

  // epilogue
  #pragma unroll
  for (int mi = 0; mi < 2; ++mi)
    #pragma unroll
    for (int ni = 0; ni < 2; ++ni) {
      int colg = n0 + wcol + ni * 16 + c16;
      #pragma unroll
      for (int r = 0; r < 4; ++r) {
        size_t o = (row0 + mi * 16 + kg * 4 + r) * 128 + colg;
        if (DUAL) {
          out[o]  = acc[0][mi][ni][r] + bias[colg];
          out2[o] = acc[NW - 1][mi][ni][r] + bias2[colg];
        } else if (NW == 3) {
          float g = fmaxf(acc[0][mi][ni][r] + bias[colg], 0.f)
                  + fmaxf(acc[1][mi][ni][r] + bias[128 + colg], 0.f)
                  + fmaxf(acc[2][mi][ni][r] + bias[256 + colg], 0.f);
          out[o] = g;
        } else {
          float g = acc[0][mi][ni][r] + bias[colg];
          if (RELU) g = fmaxf(g, 0.f);
          if (RES) g += res[o];
          out[o] = g;
        }
      }
    }
}

// ======================= f32 GEMM (tiny classifier matmul) =======================
__global__ __launch_bounds__(256) void gemm_k128(
    const float* __restrict__ A, const float* __restrict__ W,
    const float* __restrict__ bias, const float* __restrict__ res,
    float* __restrict__ out, int M, int do_relu) {
  __shared__ float As[8][64];
  __shared__ float Ws[8][128];
  int tid = threadIdx.x;
  int tx = tid & 15;
  int ty = tid >> 4;
  int row0 = blockIdx.x * 64;
  if (row0 >= M) return;
  const float* Ab = A + (size_t)row0 * DD;

  float acc[4][8];
  #pragma unroll
  for (int i = 0; i < 4; ++i)
    #pragma unroll
    for (int j = 0; j < 8; ++j) acc[i][j] = 0.f;

  for (int k0 = 0; k0 < 128; k0 += 8) {
    {
      int e = tid * 2;
      int r = e >> 3, kk = e & 7;
      float2 av = *(const float2*)&Ab[r * DD + k0 + kk];
      As[kk][r] = av.x;
      As[kk + 1][r] = av.y;
    }
    {
      int kk = tid >> 5, c = (tid & 31) * 4;
      float4 wv = *(const float4*)&W[(k0 + kk) * DD + c];
      *(float4*)&Ws[kk][c] = wv;
    }
    __syncthreads();
    #pragma unroll
    for (int kk = 0; kk < 8; ++kk) {
      float4 a4 = *(const float4*)&As[kk][ty * 4];
      float4 b0 = *(const float4*)&Ws[kk][tx * 8];
      float4 b1 = *(const float4*)&Ws[kk][tx * 8 + 4];
      float av[4] = {a4.x, a4.y, a4.z, a4.w};
      float bv[8] = {b0.x, b0.y, b0.z, b0.w, b1.x, b1.y, b1.z, b1.w};
      #pragma unroll
      for (int i = 0; i < 4; ++i)
        #pragma unroll
        for (int j = 0; j < 8; ++j) acc[i][j] += av[i] * bv[j];
    }
    __syncthreads();
  }
  #pragma unroll
  for (int i = 0; i < 4; ++i) {
    int r = row0 + ty * 4 + i;
    size_t base = (size_t)r * DD + tx * 8;
    #pragma unroll
    for (int j = 0; j < 8; ++j) {
      float g = acc[i][j];
      if (bias) g += bias[tx * 8 + j];
      if (do_relu) g = fmaxf(g, 0.f);
      if (res) g += res[base + j];
      out[base + j] = g;
    }
  }
}

// ======================= edge aggregation (f32 out) =======================
__global__ __launch_bounds__(256) void agg4_kernel(
    const float* __restrict__ H, const int* __restrict__ rp, const int* __restrict__ col,
    const float* __restrict__ wgt, const float* __restrict__ dinv,
    float* __restrict__ out) {
  int g = blockIdx.x * 256 + threadIdx.x;
  int node = g >> 5;
  int l = g & 31;
  const float4* H4 = (const float4*)H;
  float dv = dinv[node];
  float4 acc = H4[(size_t)node * 32 + l];
  float sn = dv * dv;
  acc.x *= sn; acc.y *= sn; acc.z *= sn; acc.w *= sn;
  int beg = rp[node], end = rp[node + 1];
  for (int j = beg; j < end; ++j) {
    float w = wgt[j];
    int c = col[j];
    float4 hv = H4[(size_t)c * 32 + l];
    acc.x += w * hv.x; acc.y += w * hv.y; acc.z += w * hv.z; acc.w += w * hv.w;
  }
  ((float4*)out)[(size_t)node * 32 + l] = acc;
}

// ======================= per-node double dot product =======================
__global__ __launch_bounds__(256) void dot2_kernel(
    const float* __restrict__ X, const float* __restrict__ w1, const float* __restrict__ w2,
    float* __restrict__ t1, float* __restrict__ t2) {
  int node = (blockIdx.x * 256 + threadIdx.x) >> 6;
  int lane = threadIdx.x & 63;
  if (node >= N_NODES) return;
  const float* xr = X + (size_t)node * DD;
  float a = xr[lane], b = xr[lane + 64];
  float s1 = a * w1[lane] + b * w1[lane + 64];
  float s2 = a * w2[lane] + b * w2[lane + 64];
  #pragma unroll
  for (int off = 32; off > 0; off >>= 1) {
    s1 += __shfl_down(s1, off);
    s2 += __shfl_down(s2, off);
  }
  if (lane == 0) { t1[node] = s1; t2[node] = s2; }
}

// ======================= GLA score =======================
__global__ void score_kernel(const float* __restrict__ t1, const float* __restrict__ t2,
                             const int* __restrict__ rp, const int* __restrict__ col,
                             const float* __restrict__ wgt, const float* __restrict__ dinv,
                             const float* __restrict__ b1p, const float* __restrict__ b2p,
                             float* __restrict__ out) {
  int i = blockIdx.x * 256 + threadIdx.x;
  if (i >= N_NODES) return;
  float dv = dinv[i];
  float a2 = dv * dv * t2[i] + b2p[0];
  int beg = rp[i], end = rp[i + 1];
  for (int j = beg; j < end; ++j) a2 += wgt[j] * t2[col[j]];
  out[i] = 0.5f * (t1[i] + b1p[0]) + 0.5f * a2;
}

// ======================= layer-weight softmax + combine (float4) =======================
__global__ void xf_kernel(const float* __restrict__ x1, const float* __restrict__ x2,
                          const float* __restrict__ x3, const float* __restrict__ sc,
                          float* __restrict__ xf) {
  size_t idx = (size_t)blockIdx.x * 256 + threadIdx.x;   // over N_NODES*32
  int i = (int)(idx >> 5);
  float s0 = sc[i], s1 = sc[N_NODES + i], s2 = sc[2 * N_NODES + i];
  float mx = fmaxf(s0, fmaxf(s1, s2));
  float e0 = __expf(s0 - mx), e1 = __expf(s1 - mx), e2 = __expf(s2 - mx);
  float inv = 1.f / (e0 + e1 + e2);
  e0 *= inv; e1 *= inv; e2 *= inv;
  float4 a = ((const float4*)x1)[idx];
  float4 b = ((const float4*)x2)[idx];
  float4 c = ((const float4*)x3)[idx];
  float4 o;
  o.x = e0 * a.x + e1 * b.x + e2 * c.x;
  o.y = e0 * a.y + e1 * b.y + e2 * c.y;
  o.z = e0 * a.z + e1 * b.z + e2 * c.z;
  o.w = e0 * a.w + e1 * b.w + e2 * c.w;
  ((float4*)xf)[idx] = o;
}

// ======================= top-k (stable descending) =======================
__global__ __launch_bounds__(512) void topk_kernel(const float* __restrict__ score,
                                                   int* __restrict__ idxO, float* __restrict__ valO) {
  int b = blockIdx.x;
  int t = threadIdx.x;
  __shared__ float s[512];
  float v = score[b * NPG + t];
  s[t] = v;
  __syncthreads();
  int rank = 0;
  for (int j = 0; j < 512; ++j) {
    float u = s[j];
    rank += (u > v) || (u == v && j < t);
  }
  if (rank < RATIO_K) { idxO[b * RATIO_K + rank] = t; valO[b * RATIO_K + rank] = v; }
}

// ======================= pooled gather * tanh(val) =======================
__global__ void xp_kernel(const float* __restrict__ xf, const int* __restrict__ idx,
                          const float* __restrict__ vals, float* __restrict__ xp) {
  size_t e = (size_t)blockIdx.x * 256 + threadIdx.x;
  int b = (int)(e >> 14);
  int r = (int)((e >> 7) & 127);
  int f = (int)(e & 127);
  float tv = tanhf(vals[b * RATIO_K + r]);
  int node = idx[b * RATIO_K + r];
  xp[e] = xf[((size_t)b * NPG + node) * DD + f] * tv;
}

// ======================= MFMA flash attention =======================
__global__ __launch_bounds__(256) void attn_mfma_kernel(
    const float* __restrict__ Q, const float* __restrict__ K,
    const float* __restrict__ V, float* __restrict__ O) {
  int bb = blockIdx.x >> 2, h = blockIdx.x & 3;
  int tid = threadIdx.x;
  int wave = tid >> 6, lane = tid & 63;
  int c16 = lane & 15, kg = lane >> 4;
  int qbase = wave * 32;
  const float cscale = 0.088388347648318447f;

  __shared__ float Vs[64][34];
  __shared__ unsigned char PwB[4][32 * 144];

  bf16x8 Qh[2], Ql[2];
  #pragma unroll
  for (int qt = 0; qt < 2; ++qt) {
    const float* qp = Q + ((size_t)bb * 128 + qbase + qt * 16 + c16) * 128 + h * 32 + kg * 8;
    float4 f0 = *(const float4*)qp;
    float4 f1 = *(const float4*)(qp + 4);
    float f[8] = {f0.x, f0.y, f0.z, f0.w, f1.x, f1.y, f1.z, f1.w};
    U8 hh, ll;
    #pragma unroll
    for (int j = 0; j < 8; ++j) { hh.u[j] = f2b(f[j]); ll.u[j] = f2b(f[j] - b2f(hh.u[j])); }
    Qh[qt] = hh.v; Ql[qt] = ll.v;
  }

  float m2[2] = {-3.0e38f, -3.0e38f};
  float l2[2] = {0.f, 0.f};
  f32x4 od[2][2];
  #pragma unroll
  for (int dt = 0; dt < 2; ++dt)
    #pragma unroll
    for (int qt = 0; qt < 2; ++qt) od[dt][qt] = (f32x4){0.f, 0.f, 0.f, 0.f};

  for (int kc = 0; kc < NPG; kc += 64) {
    if (kc) __syncthreads();
    {
      int j = tid >> 2, grp = tid & 3;
      const float* vp = V + ((size_t)bb * NPG + kc + j) * 128 + h * 32 + grp * 8;
      float4 v0 = *(const float4*)vp;
      float4 v1 = *(const float4*)(vp + 4);
      float* d = &Vs[j][grp * 8];
      *(float2*)&d[0] = make_float2(v0.x, v0.y);
      *(float2*)&d[2] = make_float2(v0.z, v0.w);
      *(float2*)&d[4] = make_float2(v1.x, v1.y);
      *(float2*)&d[6] = make_float2(v1.z, v1.w);
    }
    __syncthreads();

    f32x4 sac[2][4];
    #pragma unroll
    for (int qt = 0; qt < 2; ++qt)
      #pragma unroll
      for (int kt = 0; kt < 4; ++kt) sac[qt][kt] = (f32x4){0.f, 0.f, 0.f, 0.f};

    #pragma unroll
    for (int kt = 0; kt < 4; ++kt) {
      const float* kp = K + ((size_t)bb * NPG + kc + kt * 16 + c16) * 128 + h * 32 + kg * 8;
      float4 f0 = *(const float4*)kp;
      float4 f1 = *(const float4*)(kp + 4);
      float f[8] = {f0.x, f0.y, f0.z, f0.w, f1.x, f1.y, f1.z, f1.w};
      U8 hh, ll;
      #pragma unroll
      for (int j = 0; j < 8; ++j) { hh.u[j] = f2b(f[j]); ll.u[j] = f2b(f[j] - b2f(hh.u[j])); }
      #pragma unroll
      for (int qt = 0; qt < 2; ++qt) {
        sac[qt][kt] = __builtin_amdgcn_mfma_f32_16x16x32_bf16(hh.v, Qh[qt], sac[qt][kt], 0, 0, 0);
        sac[qt][kt] = __builtin_amdgcn_mfma_f32_16x16x32_bf16(hh.v, Ql[qt], sac[qt][kt], 0, 0, 0);
        sac[qt][kt] = __builtin_amdgcn_mfma_f32_16x16x32_bf16(ll.v, Qh[qt], sac[qt][kt], 0, 0, 0);
      }
    }

    float pj[2][16];
    float scl2[2];
    #pragma unroll
    for (int qt = 0; qt < 2; ++qt) {
      float mc = -3.0e38f;
      #pragma unroll
      for (int kt = 0; kt < 4; ++kt)
        #pragma unroll
        for (int r = 0; r < 4; ++r) {
          float v = sac[qt][kt][r] * cscale;
          pj[qt][kt * 4 + r] = v;
          mc = fmaxf(mc, v);
        }
      mc = fmaxf(mc, __shfl_xor(mc, 16));
      mc = fmaxf(mc, __shfl_xor(mc, 32));
      float mnew = fmaxf(m2[qt], mc);
      float scl = __expf(m2[qt] - mnew);
      float ls = 0.f;
      #pragma unroll
      for (int i = 0; i < 16; ++i) {
        float e = __expf(pj[qt][i] - mnew);
        pj[qt][i] = e;
        ls += e;
      }
      ls += __shfl_xor(ls, 16);
      ls += __shfl_xor(ls, 32);
      l2[qt] = l2[qt] * scl + ls;
      m2[qt] = mnew;
      scl2[qt] = scl;
    }
    #pragma unroll
    for (int dt = 0; dt < 2; ++dt)
      #pragma unroll
      for (int qt = 0; qt < 2; ++qt) {
        #pragma unroll
        for (int r = 0; r < 4; ++r) od[dt][qt][r] *= scl2[qt];
      }

    #pragma unroll
    for (int qt = 0; qt < 2; ++qt) {
      int q32 = qt * 16 + c16;
      unsigned char* pb = &PwB[wave][q32 * 144];
      unsigned sw = (unsigned)((q32 & 7) << 4);
      #pragma unroll
      for (int kt = 0; kt < 4; ++kt)
        #pragma unroll
        for (int rp = 0; rp < 2; ++rp) {
          unsigned pk = (unsigned)f2b(pj[qt][kt * 4 + 2 * rp]) |
                        ((unsigned)f2b(pj[qt][kt * 4 + 2 * rp + 1]) << 16);
          *(unsigned*)&pb[((unsigned)(kt * 32 + kg * 8 + 4 * rp)) ^ sw] = pk;
        }
    }

    #pragma unroll
    for (int kw = 0; kw < 2; ++kw) {
      bf16x8 Pb[2];
      #pragma unroll
      for (int qt = 0; qt < 2; ++qt) {
        int q32 = qt * 16 + c16;
        Pb[qt] = *(const bf16x8*)&PwB[wave][q32 * 144 +
                   (((unsigned)(kw * 64 + kg * 16)) ^ ((unsigned)((q32 & 7) << 4)))];
      }
      #pragma unroll
      for (int dt = 0; dt < 2; ++dt) {
        U8 vh, vl;
        #pragma unroll
        for (int j = 0; j < 8; ++j) {
          float v = Vs[kw * 32 + kg * 8 + j][dt * 16 + c16];
          vh.u[j] = f2b(v);
          vl.u[j] = f2b(v - b2f(vh.u[j]));
        }
        #pragma unroll
        for (int qt = 0; qt < 2; ++qt) {
          od[dt][qt] = __builtin_amdgcn_mfma_f32_16x16x32_bf16(vh.v, Pb[qt], od[dt][qt], 0, 0, 0);
          od[dt][qt] = __builtin_amdgcn_mfma_f32_16x16x32_bf16(vl.v, Pb[qt], od[dt][qt], 0, 0, 0);
        }
      }
    }
  }

  #pragma unroll
  for (int qt = 0; qt < 2; ++qt) {
    float inv = 1.f / l2[qt];
    size_t row = (size_t)bb * 128 + qbase + qt * 16 + c16;
    #pragma unroll
    for (int dt = 0; dt < 2; ++dt)
      #pragma unroll
      for (int r = 0; r < 4; ++r) {
        int colg = h * 32 + dt * 16 + kg * 4 + r;
        O[row * 128 + colg] = Q[row * 128 + colg] + od[dt][qt][r] * inv;
      }
  }
}

// ======================= conv1d readout =======================
__global__ void readout_kernel(const float* __restrict__ O2, const float* __restrict__ ro_w,
                               const float* __restrict__ ro_b, float* __restrict__ xg) {
  int idx = blockIdx.x * 256 + threadIdx.x;
  int b = idx >> 7, d = idx & 127;
  float s = ro_b[0];
  for (int r = 0; r < RATIO_K; ++r) s += ro_w[r] * O2[((size_t)b * RATIO_K + r) * DD + d];
  xg[idx] = s;
}

// ======================= classifier head =======================
__global__ __launch_bounds__(64) void head_kernel(const float* __restrict__ hc,
                                                  const float* __restrict__ c2w,
                                                  const float* __restrict__ c2b,
                                                  float* __restrict__ out) {
  int b = blockIdx.x, t = threadIdx.x;
  __shared__ float z[10];
  __shared__ float lse_s;
  if (t < 10) {
    float s = c2b[t];
    for (int k = 0; k < 128; ++k) s += hc[b * 128 + k] * c2w[k * 10 + t];
    z[t] = s;
  }
  __syncthreads();
  if (t == 0) {
    float mx = z[0];
    for (int c = 1; c < 10; ++c) mx = fmaxf(mx, z[c]);
    float sum = 0.f;
    for (int c = 0; c < 10; ++c) sum += expf(z[c] - mx);
    lse_s = mx + logf(sum);
  }
  __syncthreads();
  if (t < 10) out[b * 10 + t] = z[t] - lse_s;
}

// ======================= launcher =======================
extern "C" void kernel_launch(void* const* d_in, const int* in_sizes, int n_in,
                              void* d_out, int out_size, void* d_ws, size_t ws_size,
                              hipStream_t stream) {
  const float* x       = (const float*)d_in[0];
  const int*   edge    = (const int*)d_in[1];
  const float* enc_w   = (const float*)d_in[2];
  const float* enc_b   = (const float*)d_in[3];
  const float* gconv_w = (const float*)d_in[4];
  const float* gconv_b = (const float*)d_in[5];
  const float* wg1_w   = (const float*)d_in[6];
  const float* wg1_b   = (const float*)d_in[7];
  const float* wg2_w   = (const float*)d_in[8];
  const float* wg2_b   = (const float*)d_in[9];
  const float* pg1_w   = (const float*)d_in[10];
  const float* pg1_b   = (const float*)d_in[11];
  const float* pg2_w   = (const float*)d_in[12];
  const float* pg2_b   = (const float*)d_in[13];
  const float* q_w     = (const float*)d_in[14];
  const float* q_b     = (const float*)d_in[15];
  const float* k_w     = (const float*)d_in[16];
  const float* k_b     = (const float*)d_in[17];
  const float* v_w     = (const float*)d_in[18];
  const float* v_b     = (const float*)d_in[19];
  const float* o_w     = (const float*)d_in[20];
  const float* o_b     = (const float*)d_in[21];
  const float* ro_w    = (const float*)d_in[22];
  const float* ro_b    = (const float*)d_in[23];
  const float* c1_w    = (const float*)d_in[24];
  const float* c1_b    = (const float*)d_in[25];
  const float* c2_w    = (const float*)d_in[26];
  const float* c2_b    = (const float*)d_in[27];

  float* outp = (float*)d_out;

  const size_t S = (size_t)N_NODES * DD;
  float* ws    = (float*)d_ws;
  float* slot0 = ws;            // h, then xf
  float* slot1 = ws + S;        // x1, then K
  float* slot2 = ws + 2 * S;    // x2, then V
  float* slot3 = ws + 3 * S;    // x3, then xp/Q/O/O2
  float* smallf = ws + 4 * S;
  int*   cnt  = (int*)smallf;
  int*   fill = cnt + N_NODES;
  int*   rp   = fill + N_NODES;
  int*   col  = rp + N_NODES + 8;
  float* wgt  = (float*)(col + NE);
  float* dinv = wgt + NE;
  float* sc   = dinv + N_NODES;
  float* t1   = sc + 3 * N_NODES;
  float* t2   = t1 + N_NODES;
  float* score = t2 + N_NODES;
  int*   tidx = (int*)(score + N_NODES);
  float* tval = (float*)(tidx + BGRAPH * RATIO_K);
  float* hcbuf = tval + BGRAPH * RATIO_K;
  unsigned short* wsW = (unsigned short*)(hcbuf + BGRAPH * DD);  // 14 * 49152 ushorts
  float* aggbuf = (float*)(wsW + 14 * 49152);                    // S floats (32 MB)

  const size_t SP = (size_t)BGRAPH * RATIO_K * DD;
  float* xp = slot3;
  float* Qm = slot3 + SP;
  float* Om = slot3 + 2 * SP;
  float* O2 = slot3 + 3 * SP;

  // ---- graph preprocessing ----
  hipMemsetAsync(cnt, 0, N_NODES * sizeof(int), stream);
  hipMemsetAsync(fill, 0, N_NODES * sizeof(int), stream);
  count_kernel<<<NE / 256, 256, 0, stream>>>(edge + NE, cnt);
  dinv_kernel<<<N_NODES / 256, 256, 0, stream>>>(cnt, dinv);
  scan_kernel2<<<BGRAPH, 512, 0, stream>>>(cnt, rp);
  scatter_kernel<<<NE / 256, 256, 0, stream>>>(edge, rp, fill, dinv, col, wgt);

  // ---- weight prep (one launch, 14 mats) ----
  WPtrs wp;
  wp.p[0] = enc_w;
  for (int i = 0; i < 9; ++i) wp.p[1 + i] = gconv_w + (size_t)i * DD * DD;
  wp.p[10] = k_w; wp.p[11] = v_w; wp.p[12] = q_w; wp.p[13] = o_w;
  wprep_all<<<dim3(64, 14), 256, 0, stream>>>(wp, wsW);

  // ---- encoder (reads x f32 directly; split in-register) ----
  mfma_gemm8<1, false, false, false><<<dim3(2, 1024), 256, 0, stream>>>(
      x, wsW, enc_b, nullptr, nullptr, slot0, nullptr);

  // ---- 3 GCN layers: agg (f32) once, fused 3-matrix MFMA GEMM ----
  float* lin[4] = {slot0, slot1, slot2, slot3};
  const int AGG_GRID = (N_NODES * 32) / 256;
  for (int l = 0; l < 3; ++l) {
    const float* hin = lin[l];
    float* hout = lin[l + 1];
    agg4_kernel<<<AGG_GRID, 256, 0, stream>>>(hin, rp, col, wgt, dinv, aggbuf);
    mfma_gemm8<3, true, false, false><<<dim3(2, 1024), 256, 0, stream>>>(
        aggbuf, wsW + (size_t)(1 + l * 3) * 49152, gconv_b + (size_t)l * 3 * DD,
        nullptr, nullptr, hout, nullptr);
    dot2_kernel<<<N_NODES / 4, 256, 0, stream>>>(hout, wg1_w, wg2_w, t1, t2);
    score_kernel<<<N_NODES / 256, 256, 0, stream>>>(t1, t2, rp, col, wgt, dinv, wg1_b, wg2_b, sc + (size_t)l * N_NODES);
  }

  // ---- xf ----
  float* xf = slot0;
  xf_kernel<<<(N_NODES * 32) / 256, 256, 0, stream>>>(slot1, slot2, slot3, sc, xf);

  // ---- pooling score + top-k ----
  dot2_kernel<<<N_NODES / 4, 256, 0, stream>>>(xf, pg1_w, pg2_w, t1, t2);
  score_kernel<<<N_NODES / 256, 256, 0, stream>>>(t1, t2, rp, col, wgt, dinv, pg1_b, pg2_b, score);
  topk_kernel<<<BGRAPH, 512, 0, stream>>>(score, tidx, tval);
  xp_kernel<<<(BGRAPH * RATIO_K * DD) / 256, 256, 0, stream>>>(xf, tidx, tval, xp);

  // ---- Q (reads xp f32 directly) ----
  mfma_gemm8<1, false, false, false><<<dim3(2, 256), 256, 0, stream>>>(
      xp, wsW + 12 * 49152UL, q_b, nullptr, nullptr, Qm, nullptr);

  // ---- shared aggregation of xf (f32); fused K+V GEMM ----
  agg4_kernel<<<AGG_GRID, 256, 0, stream>>>(xf, rp, col, wgt, dinv, aggbuf);
  mfma_gemm8<2, false, false, true><<<dim3(2, 1024), 256, 0, stream>>>(
      aggbuf, wsW + 10 * 49152UL, k_b, v_b, nullptr, slot1, slot2);

  // ---- attention (MFMA flash) ----
  attn_mfma_kernel<<<BGRAPH * NHEAD, 256, 0, stream>>>(Qm, slot1, slot2, Om);

  // ---- O2 = Om + relu(Om @ o_w + o_b) (reads Om f32 directly) ----
  mfma_gemm8<1, true, true, false><<<dim3(2, 256), 256, 0, stream>>>(
      Om, wsW + 13 * 49152UL, o_b, nullptr, Om, O2, nullptr);

  // ---- readout -> xg ----
  float* xg = outp + BGRAPH * 10;
  readout_kernel<<<(BGRAPH * DD) / 256, 256, 0, stream>>>(O2, ro_w, ro_b, xg);

  // ---- classifier ----
  gemm_k128<<<BGRAPH / 64, 256, 0, stream>>>(xg, c1_w, c1_b, nullptr, hcbuf, BGRAPH, 1);
  head_kernel<<<BGRAPH, 64, 0, stream>>>(hcbuf, c2_w, c2_b, outp);
}